// Round 1
// 958.565 us; speedup vs baseline: 1.4245x; 1.4245x over previous
//
#include <hip/hip_runtime.h>

#define Bn  32
#define Nn  12000
#define Tn  20000
#define N1n 4000
#define N2n 1000
#define NXn 5000   // N1+N2

// ---------------- workspace layout (floats) ----------------
// PT   [12000][3][32]  batch-modified point coords, b-fastest   1,152,000
// DYZT [20000][32]     dyT, later reused as dzT                   640,000
// CYT  [4000][32]      coeffy*fy transposed                       128,000
// CY   [32][4000]      coeffy                                     128,000
// CZ   [32][5000]      coeffz                                     160,000
// VOL/VOLC/A/FY/FZ scalars
#define OFF_PT    0
#define OFF_DYZT  1152000
#define OFF_CYT   1792000
#define OFF_CY    1920000
#define OFF_CZ    2048000
#define OFF_VOL   2208000
#define OFF_VOLC  2208032
#define OFF_A     2208064
#define OFF_FY    2208096
#define OFF_FZ    2208128

// ---------------- K0: build PT[i][c][b] ----------------
__global__ void k_prep(const float* __restrict__ x, const float* __restrict__ y,
                       const float* __restrict__ pz, float* __restrict__ PT)
{
  int idx = blockIdx.x * 256 + threadIdx.x;
  if (idx >= Nn * 96) return;
  int b  = idx & 31;
  int rc = idx >> 5;           // i*3 + c
  int i  = rc / 3;
  int c  = rc - i * 3;
  float v;
  if (i < N1n) {
    v = x[(size_t)b * (N1n * 3) + i * 3 + c];
  } else if (i < NXn) {
    v = (c == 1) ? pz[3 * i + 1]
                 : y[(size_t)b * (N2n * 2) + (i - N1n) * 2 + (c >> 1)];
  } else {
    v = pz[3 * i + c];
  }
  PT[idx] = v;
}

// ---------------- K0b: vol_const from zero geometry ----------------
__global__ void k_volc(const float* __restrict__ pz, const int* __restrict__ tri,
                       float* __restrict__ volc)
{
  int t = blockIdx.x * 256 + threadIdx.x;
  float acc = 0.f;
  if (t < Tn) {
    int i0 = tri[3 * t], i1 = tri[3 * t + 1], i2 = tri[3 * t + 2];
    float q0x = pz[3 * i0], q0y = pz[3 * i0 + 1], q0z = pz[3 * i0 + 2];
    float q1x = pz[3 * i1], q1y = pz[3 * i1 + 1], q1z = pz[3 * i1 + 2];
    float q2x = pz[3 * i2], q2y = pz[3 * i2 + 1], q2z = pz[3 * i2 + 2];
    float dy0 = ((q0x - q1x) * (q2z - q1z) - (q0z - q1z) * (q2x - q1x)) * (1.0f / 6.0f);
    acc = (q0y + q1y + q2y) * dy0;
  }
  __shared__ float red[256];
  red[threadIdx.x] = acc;
  __syncthreads();
  for (int off = 128; off; off >>= 1) {
    if (threadIdx.x < off) red[threadIdx.x] += red[threadIdx.x + off];
    __syncthreads();
  }
  if (threadIdx.x == 0) atomicAdd(volc, red[0]);
}

// ---------------- K1: dy (t-major [t][b]) + per-batch volume ----------------
__global__ void k_dy_vol(const float* __restrict__ PT, const int* __restrict__ tri,
                         float* __restrict__ dyT, float* __restrict__ vol)
{
  const int tid = threadIdx.x;
  const int b  = tid & 31;
  const int tl = tid >> 5;           // 0..7
  float accV = 0.f;
  for (int t = blockIdx.x * 8 + tl; t < Tn; t += gridDim.x * 8) {
    const int i0 = tri[3 * t], i1 = tri[3 * t + 1], i2 = tri[3 * t + 2];
    const float* P0 = PT + (size_t)i0 * 96;
    const float* P1 = PT + (size_t)i1 * 96;
    const float* P2 = PT + (size_t)i2 * 96;
    float p0x = P0[b], p0y = P0[32 + b], p0z = P0[64 + b];
    float p1x = P1[b], p1y = P1[32 + b], p1z = P1[64 + b];
    float p2x = P2[b], p2y = P2[32 + b], p2z = P2[64 + b];
    float dy = ((p0x - p1x) * (p2z - p1z) - (p0z - p1z) * (p2x - p1x)) * (1.0f / 6.0f);
    dyT[(size_t)t * 32 + b] = dy;
    accV += (p0y + p1y + p2y) * dy;
  }
  __shared__ float red[256];
  red[tid] = accV;
  __syncthreads();
  if (tl == 0) {
    float s = accV;
    #pragma unroll
    for (int q = 1; q < 8; ++q) s += red[q * 32 + b];
    atomicAdd(&vol[b], s);
  }
}

// ---------------- K2b: coeffyT[i][b] = coeffy[b][i]*fy[b] ----------------
__global__ void k_prep2(const float* __restrict__ coeffy, const float* __restrict__ fy,
                        float* __restrict__ cyT)
{
  int idx = blockIdx.x * 256 + threadIdx.x;
  if (idx >= N1n * 32) return;
  int b = idx & 31, i = idx >> 5;
  cyT[idx] = coeffy[(size_t)b * N1n + i] * fy[b];
}

// ---------------- K3: dz (t-major) with corrected y ----------------
__global__ void k_dz(const float* __restrict__ PT, const int* __restrict__ tri,
                     const float* __restrict__ cyT, float* __restrict__ dzT)
{
  const int tid = threadIdx.x;
  const int b  = tid & 31;
  const int tl = tid >> 5;
  for (int t = blockIdx.x * 8 + tl; t < Tn; t += gridDim.x * 8) {
    const int i0 = tri[3 * t], i1 = tri[3 * t + 1], i2 = tri[3 * t + 2];
    const float* P0 = PT + (size_t)i0 * 96;
    const float* P1 = PT + (size_t)i1 * 96;
    const float* P2 = PT + (size_t)i2 * 96;
    float p0x = P0[b], p0y = P0[32 + b];
    float p1x = P1[b], p1y = P1[32 + b];
    float p2x = P2[b], p2y = P2[32 + b];
    if (i0 < N1n) p0y += cyT[(size_t)i0 * 32 + b];
    if (i1 < N1n) p1y += cyT[(size_t)i1 * 32 + b];
    if (i2 < N1n) p2y += cyT[(size_t)i2 * 32 + b];
    float dz = ((p0x - p2x) * (p1y - p2y) - (p0y - p2y) * (p1x - p2x)) * (1.0f / 6.0f);
    dzT[(size_t)t * 32 + b] = dz;
  }
}

// ---------------- split-K GEMM: C[b][j] += sum_t A[t][b] * V[j][t] ----------------
// block: 256 threads; tile 32b x 128j; KT=16; thread tile 4b x 4j
// bg = tid&7 (4 b each), jg = tid>>3 (4 j each)
// inner reads: sA broadcast (8 addrs/wave), sB broadcast (8 addrs/wave) -> conflict-free
#define KT     16
#define JT     128
#define SVS    132      // 132 % 32 == 4 -> staging transpose writes are 2-way (free)
#define KCHUNK 800      // 25 k-chunks over T=20000

__global__ __launch_bounds__(256, 4)
void k_gemm(const float* __restrict__ A,   // [Tn][32] t-major
            const float* __restrict__ V,   // [NJ][Tn]
            float* __restrict__ C,         // [Bn][NJ]
            int NJ)
{
  __shared__ float sA[KT * 32];      // 2 KB
  __shared__ float sB[KT * SVS];     // 8.25 KB
  const int tid = threadIdx.x;
  const int t0  = blockIdx.x * KCHUNK;
  const int jb  = blockIdx.y * JT;
  const int bg  = tid & 7;
  const int jg  = tid >> 3;
  const int rr  = tid >> 2;          // 0..63 (staging row)
  const int tc4 = (tid & 3) * 4;     // 0,4,8,12

  float acc[4][4] = {{0.f}};

  for (int tk = t0; tk < t0 + KCHUNK; tk += KT) {
    __syncthreads();
    // stage A: 16t x 32b = 512 floats, contiguous
    if (tid < 128)
      *(float4*)(sA + tid * 4) = *(const float4*)(A + (size_t)tk * 32 + tid * 4);
    // stage B transposed: sB[k][j], 128 rows x 16 t (64B per row from global)
    #pragma unroll
    for (int p = 0; p < 2; ++p) {
      int r   = p * 64 + rr;
      int jgl = jb + r;
      float4 v = make_float4(0.f, 0.f, 0.f, 0.f);
      if (jgl < NJ) v = *(const float4*)(V + (size_t)jgl * Tn + tk + tc4);
      sB[(tc4 + 0) * SVS + r] = v.x;
      sB[(tc4 + 1) * SVS + r] = v.y;
      sB[(tc4 + 2) * SVS + r] = v.z;
      sB[(tc4 + 3) * SVS + r] = v.w;
    }
    __syncthreads();
    #pragma unroll
    for (int kk = 0; kk < KT; ++kk) {
      float4 a  = *(const float4*)(sA + kk * 32 + bg * 4);
      float4 bv = *(const float4*)(sB + kk * SVS + jg * 4);
      const float av[4] = {a.x, a.y, a.z, a.w};
      const float bw[4] = {bv.x, bv.y, bv.z, bv.w};
      #pragma unroll
      for (int i = 0; i < 4; ++i)
        #pragma unroll
        for (int j = 0; j < 4; ++j)
          acc[i][j] += av[i] * bw[j];
    }
  }
  // epilogue: split-K combine via fp32 atomics (25 hits per element)
  #pragma unroll
  for (int i = 0; i < 4; ++i) {
    int b = bg * 4 + i;
    #pragma unroll
    for (int j = 0; j < 4; ++j) {
      int jgl = jb + jg * 4 + j;
      if (jgl < NJ) atomicAdd(&C[(size_t)b * NJ + jgl], acc[i][j]);
    }
  }
}

// ---------------- K2/K4: s = sum coeff^2 ; factor = a / s ----------------
__global__ void k_factor(const float* __restrict__ coeff, int NJ,
    const float* __restrict__ vol, const float* __restrict__ volc,
    float* __restrict__ aArr, float* __restrict__ factor, int computeA)
{
  const int b = blockIdx.x;
  float s = 0.f;
  for (int j = threadIdx.x; j < NJ; j += 256) {
    float v = coeff[(size_t)b * NJ + j];
    s += v * v;
  }
  __shared__ float red[256];
  red[threadIdx.x] = s;
  __syncthreads();
  for (int off = 128; off; off >>= 1) {
    if (threadIdx.x < off) red[threadIdx.x] += red[threadIdx.x + off];
    __syncthreads();
  }
  if (threadIdx.x == 0) {
    float a;
    if (computeA) { a = 0.5f * (volc[0] - vol[b]); aArr[b] = a; }
    else          { a = aArr[b]; }
    factor[b] = a / red[0];
  }
}

// ---------------- K5: assemble outputs ----------------
__global__ void k_out(const float* __restrict__ x, const float* __restrict__ y,
    const float* __restrict__ coeffy, const float* __restrict__ coeffz,
    const float* __restrict__ fy, const float* __restrict__ fz,
    float* __restrict__ out)
{
  int idx = blockIdx.x * blockDim.x + threadIdx.x;
  if (idx >= 448000) return;
  if (idx < 384000) {
    int b = idx / 12000;
    int r = idx - b * 12000;
    int i = r / 3, c = r - i * 3;
    float v = x[(size_t)b * 12000 + r];
    if (c == 1)      v += coeffy[(size_t)b * N1n + i] * fy[b];
    else if (c == 2) v += coeffz[(size_t)b * NXn + i] * fz[b];
    out[idx] = v;
  } else {
    int k = idx - 384000;
    int b = k / 2000;
    int r = k - b * 2000;
    int i = r >> 1, c = r & 1;
    float v = y[(size_t)b * 2000 + r];
    if (c) v += coeffz[(size_t)b * NXn + N1n + i] * fz[b];
    out[idx] = v;
  }
}

// ---------------- launch ----------------
extern "C" void kernel_launch(void* const* d_in, const int* in_sizes, int n_in,
                              void* d_out, int out_size, void* d_ws, size_t ws_size,
                              hipStream_t stream)
{
  const float* x   = (const float*)d_in[0];
  const float* y   = (const float*)d_in[1];
  const float* pz  = (const float*)d_in[2];
  const int*   tri = (const int*)d_in[3];
  const float* Vx  = (const float*)d_in[6];   // [N1][T]
  const float* Vxy = (const float*)d_in[7];   // [N1+N2][T]
  float* out = (float*)d_out;

  float* ws    = (float*)d_ws;
  float* PT    = ws + OFF_PT;
  float* dyzT  = ws + OFF_DYZT;    // dyT, then reused as dzT
  float* cyT   = ws + OFF_CYT;
  float* cy    = ws + OFF_CY;
  float* cz    = ws + OFF_CZ;
  float* vol   = ws + OFF_VOL;
  float* volc  = ws + OFF_VOLC;
  float* aArr  = ws + OFF_A;
  float* fy    = ws + OFF_FY;
  float* fz    = ws + OFF_FZ;

  // zero atomic-accumulated region: cy + cz + vol + volc (contiguous)
  hipMemsetAsync(cy, 0, (size_t)(128000 + 160000 + 33) * sizeof(float), stream);

  k_prep  <<<(Nn * 96 + 255) / 256, 256, 0, stream>>>(x, y, pz, PT);
  k_volc  <<<(Tn + 255) / 256,      256, 0, stream>>>(pz, tri, volc);
  k_dy_vol<<<1250,                  256, 0, stream>>>(PT, tri, dyzT, vol);
  k_gemm  <<<dim3(25, 32),          256, 0, stream>>>(dyzT, Vx, cy, N1n);
  k_factor<<<32,                    256, 0, stream>>>(cy, N1n, vol, volc, aArr, fy, 1);
  k_prep2 <<<(N1n * 32 + 255) / 256,256, 0, stream>>>(cy, fy, cyT);
  k_dz    <<<1250,                  256, 0, stream>>>(PT, tri, cyT, dyzT);
  k_gemm  <<<dim3(25, 40),          256, 0, stream>>>(dyzT, Vxy, cz, NXn);
  k_factor<<<32,                    256, 0, stream>>>(cz, NXn, vol, volc, aArr, fz, 0);
  k_out   <<<1750,                  256, 0, stream>>>(x, y, cy, cz, fy, fz, out);
}